// Round 6
// baseline (282.211 us; speedup 1.0000x reference)
//
#include <hip/hip_runtime.h>

// ---------------- constants (match reference) ----------------
// B,H,W,F,D = 8,126,126,64,32 ; grid fields are (8,128,128,32)
#define NITER 20
#define OUTER 3

constexpr double DXd  = 2.0 / 9.0;     // 2/(B+1)
constexpr double DYd  = 2.0 / 127.0;   // 2/(H+1)
constexpr double DX2d = DXd * DXd;
constexpr double DY2d = DYd * DYd;
constexpr double DENd = 2.0 * (DX2d + DY2d);

constexpr float K1     = (float)(DY2d / DENd);          // * (E+W)
constexpr float K2     = (float)(DX2d / DENd);          // * (N+S)
constexpr float CC     = (float)(DX2d * DY2d / DENd);   // c coefficient
constexpr float INV2DX = (float)(1.0 / (2.0 * DXd));
constexpr float INV2DY = (float)(1.0 / (2.0 * DYd));
constexpr float INVDT  = (float)(1.0 / 0.1);
constexpr float DTDX   = (float)(0.1 / DXd);
constexpr float DTDY   = (float)(0.1 / DYd);
constexpr float PGX    = (float)(0.1 / (2.0 * 1.0 * DXd)); // DT/(2 RHO DX)
constexpr float PGY    = (float)(0.1 / (2.0 * 1.0 * DYd));
constexpr float A1     = (float)(0.1 / DX2d);            // DT/DX2
constexpr float A2     = (float)(0.1 / DY2d);            // DT/DY2
constexpr float NUf    = 0.1f;
constexpr float FDT    = 0.1f;                           // FRC*DT

// DPP 16-lane-row rotates (VALU pipe; replaces ds_bpermute for E/W halos).
// 0x121 = ROW_ROR:1, 0x12F = ROW_ROR:15. Direction convention is resolved at
// runtime via a lane-id probe (selLower), so either HW convention is correct.
#define ROR1(x)  __int_as_float(__builtin_amdgcn_mov_dpp(__float_as_int(x), 0x121, 0xF, 0xF, false))
#define ROR15(x) __int_as_float(__builtin_amdgcn_mov_dpp(__float_as_int(x), 0x12F, 0xF, 0xF, false))
#define FROM_LO(x) (selLower ? ROR1(x) : ROR15(x))   // value from tx-1 (periodic in 16)
#define FROM_HI(x) (selLower ? ROR15(x) : ROR1(x))   // value from tx+1 (periodic in 16)

// ---------------- kernel 1: p0 = einsum(pad(x), w) + b_lin, planar [b][d][128][128]
__global__ __launch_bounds__(256) void einsum_kernel(
    const float* __restrict__ x, const float* __restrict__ w,
    const float* __restrict__ bl, float* __restrict__ p0)
{
    int id = blockIdx.x * 256 + threadIdx.x;
    int c = id & 127, r = (id >> 7) & 127, b = id >> 14;
    float acc[32];
#pragma unroll
    for (int d = 0; d < 32; ++d) acc[d] = bl[d];
    if (r >= 1 && r <= 126 && c >= 1 && c <= 126) {
        const float* xp = x + (((size_t)(b * 126 + (r - 1))) * 126 + (c - 1)) * 64;
#pragma unroll
        for (int f = 0; f < 64; f += 4) {
            float4 xv = *(const float4*)(xp + f);
#pragma unroll
            for (int d = 0; d < 32; ++d) {
                acc[d] += xv.x * w[d * 64 + f] + xv.y * w[d * 64 + f + 1]
                        + xv.z * w[d * 64 + f + 2] + xv.w * w[d * 64 + f + 3];
            }
        }
    }
    float* op = p0 + ((size_t)b * 32) * 16384 + r * 128 + c;
#pragma unroll
    for (int d = 0; d < 32; ++d) op[(size_t)d * 16384] = acc[d];
}

// ---------------- kernel 2: the full 3-outer-iteration simulation ----------------
// one workgroup per (b,d) plane; 512 threads = 16 tx (8 cols each) x 32 ty (4 rows).
//
// Round-6 structure: E/W (x-direction, periodic-128) halo exchange is done with
// DPP row_ror rotates on the VALU pipe instead of ds_bpermute on the DS pipe.
// Wave layout: 64 lanes = 4 ty-groups x 16 tx; 16 tx x 8 cols = the full 128-col
// periodic ring, so the within-16-lane DPP rotate wrap IS the domain wrap — no
// boundary fixup. (R5 post-mortem: time tracks per-phase DS work, VALUBusy
// pinned ~40% -> DS-pipe throughput-bound; Jacobi had 16 bperms/iter, now 0.)
//
// LDS 128 KiB (sP seams 64K ping-pong + sU/sV 32K each) -> 1 WG/CU ->
// VGPR budget 256 (launch_bounds(512,2)); ~160 live regs, no spill expected.
__global__ __launch_bounds__(512, 2) void sim_kernel(
    const float* __restrict__ u0, const float* __restrict__ v0,
    const float* __restrict__ p0ws, const float* __restrict__ x,
    const float* __restrict__ w, const float* __restrict__ bl,
    float* __restrict__ out, int use_ws)
{
    __shared__ float sP[2][32][2][128];  // p seam rows {0,3} per ty, ping-pong (64 KiB)
    __shared__ float sU[32][2][128];     // u seam rows {0,3} (32 KiB)
    __shared__ float sV[32][2][128];     // v seam rows {0,3} (32 KiB)

    const int tid = threadIdx.x;
    const int tx = tid & 15, ty = tid >> 4;
    const int c0 = tx << 3, r0 = ty << 2;
    const int lane = tid & 63;
    const int bb = blockIdx.x & 7;   // batch
    const int d  = blockIdx.x >> 3;  // channel
    const int tyN = (ty > 0) ? ty - 1 : 0;     // clamped: garbage masked by BC overwrite
    const int tyS = (ty < 31) ? ty + 1 : 31;

    // runtime DPP-direction probe: does ROW_ROR:1 source from lane-1 (mod 16)?
    const int pr = __builtin_amdgcn_mov_dpp(lane, 0x121, 0xF, 0xF, false);
    const bool selLower = (pr == ((lane & 48) | ((lane + 15) & 15)));

    float pC[4][8], uC[4][8], vC[4][8], cb[4][8];

    // ---- load u, v (strided channel reads, one-time) ----
#pragma unroll
    for (int r = 0; r < 4; ++r) {
        const size_t base = ((size_t)((bb * 128 + (r0 + r)) * 128 + c0)) * 32 + d;
#pragma unroll
        for (int c = 0; c < 8; ++c) {
            uC[r][c] = u0[base + (size_t)c * 32];
            vC[r][c] = v0[base + (size_t)c * 32];
        }
    }

    // ---- initial p ----
    if (use_ws) {
        const float* pp = p0ws + ((size_t)(bb * 32 + d)) * 16384;
#pragma unroll
        for (int r = 0; r < 4; ++r) {
            float4 a = *(const float4*)(pp + (r0 + r) * 128 + c0);
            float4 b = *(const float4*)(pp + (r0 + r) * 128 + c0 + 4);
            pC[r][0] = a.x; pC[r][1] = a.y; pC[r][2] = a.z; pC[r][3] = a.w;
            pC[r][4] = b.x; pC[r][5] = b.y; pC[r][6] = b.z; pC[r][7] = b.w;
        }
    } else {
        const float blv = bl[d];
#pragma unroll
        for (int r = 0; r < 4; ++r) {
            const int gr = r0 + r;
#pragma unroll
            for (int c = 0; c < 8; ++c) {
                const int gc = c0 + c;
                float acc = blv;
                if (gr >= 1 && gr <= 126 && gc >= 1 && gc <= 126) {
                    const float* xp = x + (((size_t)(bb * 126 + (gr - 1))) * 126 + (gc - 1)) * 64;
                    for (int f = 0; f < 64; f += 4) {
                        float4 xv = *(const float4*)(xp + f);
                        acc += xv.x * w[d * 64 + f] + xv.y * w[d * 64 + f + 1]
                             + xv.z * w[d * 64 + f + 2] + xv.w * w[d * 64 + f + 3];
                    }
                }
                pC[r][c] = acc;
            }
        }
    }

    // ---- initial seam publish ----
    int s = 0;
    *(float4*)&sP[0][ty][0][c0]     = make_float4(pC[0][0], pC[0][1], pC[0][2], pC[0][3]);
    *(float4*)&sP[0][ty][0][c0 + 4] = make_float4(pC[0][4], pC[0][5], pC[0][6], pC[0][7]);
    *(float4*)&sP[0][ty][1][c0]     = make_float4(pC[3][0], pC[3][1], pC[3][2], pC[3][3]);
    *(float4*)&sP[0][ty][1][c0 + 4] = make_float4(pC[3][4], pC[3][5], pC[3][6], pC[3][7]);
    *(float4*)&sU[ty][0][c0]        = make_float4(uC[0][0], uC[0][1], uC[0][2], uC[0][3]);
    *(float4*)&sU[ty][0][c0 + 4]    = make_float4(uC[0][4], uC[0][5], uC[0][6], uC[0][7]);
    *(float4*)&sU[ty][1][c0]        = make_float4(uC[3][0], uC[3][1], uC[3][2], uC[3][3]);
    *(float4*)&sU[ty][1][c0 + 4]    = make_float4(uC[3][4], uC[3][5], uC[3][6], uC[3][7]);
    *(float4*)&sV[ty][0][c0]        = make_float4(vC[0][0], vC[0][1], vC[0][2], vC[0][3]);
    *(float4*)&sV[ty][0][c0 + 4]    = make_float4(vC[0][4], vC[0][5], vC[0][6], vC[0][7]);
    *(float4*)&sV[ty][1][c0]        = make_float4(vC[3][0], vC[3][1], vC[3][2], vC[3][3]);
    *(float4*)&sV[ty][1][c0 + 4]    = make_float4(vC[3][4], vC[3][5], vC[3][6], vC[3][7]);
    __syncthreads();

    for (int outer = 0; outer < OUTER; ++outer) {
        // ================= build_b -> cb = CC * b =================
        {
            float uNh[8], uSh[8], vNh[8], vSh[8];
            {
                float4 a, b;
                a = *(const float4*)&sU[tyN][1][c0]; b = *(const float4*)&sU[tyN][1][c0 + 4];
                uNh[0]=a.x; uNh[1]=a.y; uNh[2]=a.z; uNh[3]=a.w; uNh[4]=b.x; uNh[5]=b.y; uNh[6]=b.z; uNh[7]=b.w;
                a = *(const float4*)&sU[tyS][0][c0]; b = *(const float4*)&sU[tyS][0][c0 + 4];
                uSh[0]=a.x; uSh[1]=a.y; uSh[2]=a.z; uSh[3]=a.w; uSh[4]=b.x; uSh[5]=b.y; uSh[6]=b.z; uSh[7]=b.w;
                a = *(const float4*)&sV[tyN][1][c0]; b = *(const float4*)&sV[tyN][1][c0 + 4];
                vNh[0]=a.x; vNh[1]=a.y; vNh[2]=a.z; vNh[3]=a.w; vNh[4]=b.x; vNh[5]=b.y; vNh[6]=b.z; vNh[7]=b.w;
                a = *(const float4*)&sV[tyS][0][c0]; b = *(const float4*)&sV[tyS][0][c0 + 4];
                vSh[0]=a.x; vSh[1]=a.y; vSh[2]=a.z; vSh[3]=a.w; vSh[4]=b.x; vSh[5]=b.y; vSh[6]=b.z; vSh[7]=b.w;
            }
#pragma unroll
            for (int r = 0; r < 4; ++r) {
                float uWh = FROM_LO(uC[r][7]);
                float uEh = FROM_HI(uC[r][0]);
                float vWh = FROM_LO(vC[r][7]);
                float vEh = FROM_HI(vC[r][0]);
#pragma unroll
                for (int c = 0; c < 8; ++c) {
                    float uE = (c < 7) ? uC[r][c + 1] : uEh;
                    float uW = (c > 0) ? uC[r][c - 1] : uWh;
                    float vE = (c < 7) ? vC[r][c + 1] : vEh;
                    float vW = (c > 0) ? vC[r][c - 1] : vWh;
                    float uN = (r > 0) ? uC[r - 1][c] : uNh[c];
                    float uS = (r < 3) ? uC[r + 1][c] : uSh[c];
                    float vN = (r > 0) ? vC[r - 1][c] : vNh[c];
                    float vS = (r < 3) ? vC[r + 1][c] : vSh[c];
                    float dudx = (uE - uW) * INV2DX;
                    float dvdy = (vS - vN) * INV2DY;
                    float dudy = (uS - uN) * INV2DY;
                    float dvdx = (vE - vW) * INV2DX;
                    float bt = (dudx + dvdy) * INVDT - dudx * dudx
                             - 2.0f * dudy * dvdx - dvdy * dvdy;   // RHO == 1
                    cb[r][c] = CC * bt;   // garbage at rows 0/127: masked by p BCs
                }
            }
        }

        // ================= pressure_poisson: 20 Jacobi iterations =================
        for (int it = 0; it < NITER; ++it) {
            float nrow[8], shalo[8];
            {
                float4 a, b;
                a = *(const float4*)&sP[s][tyN][1][c0]; b = *(const float4*)&sP[s][tyN][1][c0 + 4];
                nrow[0]=a.x; nrow[1]=a.y; nrow[2]=a.z; nrow[3]=a.w; nrow[4]=b.x; nrow[5]=b.y; nrow[6]=b.z; nrow[7]=b.w;
                a = *(const float4*)&sP[s][tyS][0][c0]; b = *(const float4*)&sP[s][tyS][0][c0 + 4];
                shalo[0]=a.x; shalo[1]=a.y; shalo[2]=a.z; shalo[3]=a.w; shalo[4]=b.x; shalo[5]=b.y; shalo[6]=b.z; shalo[7]=b.w;
            }
#pragma unroll
            for (int r = 0; r < 4; ++r) {
                float old0[8];   // snapshot: ALL same-row neighbors must be OLD (Jacobi)
#pragma unroll
                for (int c = 0; c < 8; ++c) old0[c] = pC[r][c];
                float pWh = FROM_LO(old0[7]);
                float pEh = FROM_HI(old0[0]);
#pragma unroll
                for (int c = 0; c < 8; ++c) {
                    float E = (c < 7) ? old0[c + 1] : pEh;
                    float W = (c > 0) ? old0[c - 1] : pWh;
                    float N = nrow[c];
                    float S = (r < 3) ? pC[r + 1][c] : shalo[c];
                    pC[r][c] = (E + W) * K1 + (N + S) * K2 - cb[r][c];
                }
#pragma unroll
                for (int c = 0; c < 8; ++c) nrow[c] = old0[c];
            }
            // row BCs (copy of NEW values); also masks the garbage edge-row computes
            if (ty == 0) {
#pragma unroll
                for (int c = 0; c < 8; ++c) pC[0][c] = pC[1][c];
            }
            if (ty == 31) {
#pragma unroll
                for (int c = 0; c < 8; ++c) pC[3][c] = pC[2][c];
            }
            // publish new seam rows into the other buffer; single barrier
            *(float4*)&sP[s ^ 1][ty][0][c0]     = make_float4(pC[0][0], pC[0][1], pC[0][2], pC[0][3]);
            *(float4*)&sP[s ^ 1][ty][0][c0 + 4] = make_float4(pC[0][4], pC[0][5], pC[0][6], pC[0][7]);
            *(float4*)&sP[s ^ 1][ty][1][c0]     = make_float4(pC[3][0], pC[3][1], pC[3][2], pC[3][3]);
            *(float4*)&sP[s ^ 1][ty][1][c0 + 4] = make_float4(pC[3][4], pC[3][5], pC[3][6], pC[3][7]);
            __syncthreads();
            s ^= 1;
        }
        // after 20 iters, s == 0 again; newest p seams in sP[s]

        // ================= velocity_step (skipped after last outer: output is p) ========
        if (outer < OUTER - 1) {
            float uNh[8], uSh[8], vNh[8], vSh[8], pNh[8], pSh[8];
            {
                float4 a, b;
                a = *(const float4*)&sU[tyN][1][c0]; b = *(const float4*)&sU[tyN][1][c0 + 4];
                uNh[0]=a.x; uNh[1]=a.y; uNh[2]=a.z; uNh[3]=a.w; uNh[4]=b.x; uNh[5]=b.y; uNh[6]=b.z; uNh[7]=b.w;
                a = *(const float4*)&sU[tyS][0][c0]; b = *(const float4*)&sU[tyS][0][c0 + 4];
                uSh[0]=a.x; uSh[1]=a.y; uSh[2]=a.z; uSh[3]=a.w; uSh[4]=b.x; uSh[5]=b.y; uSh[6]=b.z; uSh[7]=b.w;
                a = *(const float4*)&sV[tyN][1][c0]; b = *(const float4*)&sV[tyN][1][c0 + 4];
                vNh[0]=a.x; vNh[1]=a.y; vNh[2]=a.z; vNh[3]=a.w; vNh[4]=b.x; vNh[5]=b.y; vNh[6]=b.z; vNh[7]=b.w;
                a = *(const float4*)&sV[tyS][0][c0]; b = *(const float4*)&sV[tyS][0][c0 + 4];
                vSh[0]=a.x; vSh[1]=a.y; vSh[2]=a.z; vSh[3]=a.w; vSh[4]=b.x; vSh[5]=b.y; vSh[6]=b.z; vSh[7]=b.w;
                a = *(const float4*)&sP[s][tyN][1][c0]; b = *(const float4*)&sP[s][tyN][1][c0 + 4];
                pNh[0]=a.x; pNh[1]=a.y; pNh[2]=a.z; pNh[3]=a.w; pNh[4]=b.x; pNh[5]=b.y; pNh[6]=b.z; pNh[7]=b.w;
                a = *(const float4*)&sP[s][tyS][0][c0]; b = *(const float4*)&sP[s][tyS][0][c0 + 4];
                pSh[0]=a.x; pSh[1]=a.y; pSh[2]=a.z; pSh[3]=a.w; pSh[4]=b.x; pSh[5]=b.y; pSh[6]=b.z; pSh[7]=b.w;
            }
            __syncthreads();   // all seam reads done before the sU/sV rewrites below

            float uNrow[8], vNrow[8];
#pragma unroll
            for (int c = 0; c < 8; ++c) { uNrow[c] = uNh[c]; vNrow[c] = vNh[c]; }
#pragma unroll
            for (int r = 0; r < 4; ++r) {
                float uold[8], vold[8];  // snapshot: same-row W neighbors must be OLD
#pragma unroll
                for (int c = 0; c < 8; ++c) { uold[c] = uC[r][c]; vold[c] = vC[r][c]; }
                float uWh = FROM_LO(uold[7]);
                float uEh = FROM_HI(uold[0]);
                float vWh = FROM_LO(vold[7]);
                float vEh = FROM_HI(vold[0]);
                float pWh = FROM_LO(pC[r][7]);
                float pEh = FROM_HI(pC[r][0]);
#pragma unroll
                for (int c = 0; c < 8; ++c) {
                    float uc = uold[c], vc = vold[c];
                    float uE = (c < 7) ? uold[c + 1] : uEh;
                    float uW = (c > 0) ? uold[c - 1] : uWh;
                    float vE = (c < 7) ? vold[c + 1] : vEh;
                    float vW = (c > 0) ? vold[c - 1] : vWh;
                    float uN = uNrow[c];
                    float uS = (r < 3) ? uC[r + 1][c] : uSh[c];
                    float vN = vNrow[c];
                    float vS = (r < 3) ? vC[r + 1][c] : vSh[c];
                    float pE = (c < 7) ? pC[r][c + 1] : pEh;
                    float pW = (c > 0) ? pC[r][c - 1] : pWh;
                    float pN = (r > 0) ? pC[r - 1][c] : pNh[c];
                    float pS = (r < 3) ? pC[r + 1][c] : pSh[c];

                    float unew = uc - uc * DTDX * (uc - uW) - vc * DTDY * (uc - uN)
                               - PGX * (pE - pW)
                               + NUf * (A1 * (uE - 2.0f * uc + uW) + A2 * (uS - 2.0f * uc + uN))
                               + FDT;
                    float vnew = vc - uc * DTDX * (vc - vW) - vc * DTDY * (vc - vN)
                               - PGY * (pS - pN)
                               + NUf * (A1 * (vE - 2.0f * vc + vW) + A2 * (vS - 2.0f * vc + vN));
                    uC[r][c] = unew;
                    vC[r][c] = vnew;
                }
#pragma unroll
                for (int c = 0; c < 8; ++c) { uNrow[c] = uold[c]; vNrow[c] = vold[c]; }
            }
            // u,v row BCs: rows 0 and 127 -> 0 (also masks garbage edge computes)
            if (ty == 0) {
#pragma unroll
                for (int c = 0; c < 8; ++c) { uC[0][c] = 0.0f; vC[0][c] = 0.0f; }
            }
            if (ty == 31) {
#pragma unroll
                for (int c = 0; c < 8; ++c) { uC[3][c] = 0.0f; vC[3][c] = 0.0f; }
            }
            *(float4*)&sU[ty][0][c0]     = make_float4(uC[0][0], uC[0][1], uC[0][2], uC[0][3]);
            *(float4*)&sU[ty][0][c0 + 4] = make_float4(uC[0][4], uC[0][5], uC[0][6], uC[0][7]);
            *(float4*)&sU[ty][1][c0]     = make_float4(uC[3][0], uC[3][1], uC[3][2], uC[3][3]);
            *(float4*)&sU[ty][1][c0 + 4] = make_float4(uC[3][4], uC[3][5], uC[3][6], uC[3][7]);
            *(float4*)&sV[ty][0][c0]     = make_float4(vC[0][0], vC[0][1], vC[0][2], vC[0][3]);
            *(float4*)&sV[ty][0][c0 + 4] = make_float4(vC[0][4], vC[0][5], vC[0][6], vC[0][7]);
            *(float4*)&sV[ty][1][c0]     = make_float4(vC[3][0], vC[3][1], vC[3][2], vC[3][3]);
            *(float4*)&sV[ty][1][c0 + 4] = make_float4(vC[3][4], vC[3][5], vC[3][6], vC[3][7]);
            __syncthreads();
        }
    }

    // ---- output: p[:, row 127, :, :]  -> out[b][col][d] ----
    if (ty == 31) {
        float* op = out + ((size_t)bb * 128 + c0) * 32 + d;
#pragma unroll
        for (int c = 0; c < 8; ++c) op[(size_t)c * 32] = pC[3][c];
    }
}

extern "C" void kernel_launch(void* const* d_in, const int* in_sizes, int n_in,
                              void* d_out, int out_size, void* d_ws, size_t ws_size,
                              hipStream_t stream) {
    const float* x  = (const float*)d_in[0];
    const float* u0 = (const float*)d_in[1];
    const float* v0 = (const float*)d_in[2];
    const float* w  = (const float*)d_in[3];
    const float* bl = (const float*)d_in[4];
    float* out = (float*)d_out;
    float* p0  = (float*)d_ws;

    const size_t need = (size_t)8 * 32 * 128 * 128 * sizeof(float);
    const int use_ws = (ws_size >= need) ? 1 : 0;

    if (use_ws) {
        einsum_kernel<<<512, 256, 0, stream>>>(x, w, bl, p0);
    }
    sim_kernel<<<256, 512, 0, stream>>>(u0, v0, p0, x, w, bl, out, use_ws);
}

// Round 7
// 249.313 us; speedup vs baseline: 1.1320x; 1.1320x over previous
//
#include <hip/hip_runtime.h>

// ---------------- constants (match reference) ----------------
// B,H,W,F,D = 8,126,126,64,32 ; grid fields are (8,128,128,32)
#define NITER 20
#define OUTER 3

constexpr double DXd  = 2.0 / 9.0;     // 2/(B+1)
constexpr double DYd  = 2.0 / 127.0;   // 2/(H+1)
constexpr double DX2d = DXd * DXd;
constexpr double DY2d = DYd * DYd;
constexpr double DENd = 2.0 * (DX2d + DY2d);

constexpr float K1     = (float)(DY2d / DENd);          // * (E+W)
constexpr float K2     = (float)(DX2d / DENd);          // * (N+S)
constexpr float CC     = (float)(DX2d * DY2d / DENd);   // c coefficient
constexpr float INV2DX = (float)(1.0 / (2.0 * DXd));
constexpr float INV2DY = (float)(1.0 / (2.0 * DYd));
constexpr float INVDT  = (float)(1.0 / 0.1);
constexpr float DTDX   = (float)(0.1 / DXd);
constexpr float DTDY   = (float)(0.1 / DYd);
constexpr float PGX    = (float)(0.1 / (2.0 * 1.0 * DXd)); // DT/(2 RHO DX)
constexpr float PGY    = (float)(0.1 / (2.0 * 1.0 * DYd));
constexpr float A1     = (float)(0.1 / DX2d);            // DT/DX2
constexpr float A2     = (float)(0.1 / DY2d);            // DT/DY2
constexpr float NUf    = 0.1f;
constexpr float FDT    = 0.1f;                           // FRC*DT

// DPP 16-lane-row rotates (VALU pipe; E/W halo with free periodic-128 wrap).
// Verified correct in Round 6 (passed). Runtime probe resolves direction.
#define ROR1(x)  __int_as_float(__builtin_amdgcn_mov_dpp(__float_as_int(x), 0x121, 0xF, 0xF, false))
#define ROR15(x) __int_as_float(__builtin_amdgcn_mov_dpp(__float_as_int(x), 0x12F, 0xF, 0xF, false))
#define FROM_LO(x) (selLower ? ROR1(x) : ROR15(x))   // value from tx-1 (periodic in 16)
#define FROM_HI(x) (selLower ? ROR15(x) : ROR1(x))   // value from tx+1 (periodic in 16)

// Split-half LDS row layout: row of 128 cols stored as {c0..c3 of tx0..15}{c4..c7
// of tx0..15}. Every access is 16B-stride contiguous across the 16 tx -> uniform
// bank load (8/bank = b128 minimum), 0 counted conflicts. Legal because every
// address is only ever touched by the same tx (E/W comes from DPP, never LDS).
#define PLOAD(dst, plane, r) do { \
    float4 _a = *(const float4*)&(plane)[(r) * 128 + (tx << 2)]; \
    float4 _b = *(const float4*)&(plane)[(r) * 128 + 64 + (tx << 2)]; \
    (dst)[0]=_a.x; (dst)[1]=_a.y; (dst)[2]=_a.z; (dst)[3]=_a.w; \
    (dst)[4]=_b.x; (dst)[5]=_b.y; (dst)[6]=_b.z; (dst)[7]=_b.w; } while (0)
#define PSTORE(plane, r, src) do { \
    *(float4*)&(plane)[(r) * 128 + (tx << 2)] = make_float4((src)[0],(src)[1],(src)[2],(src)[3]); \
    *(float4*)&(plane)[(r) * 128 + 64 + (tx << 2)] = make_float4((src)[4],(src)[5],(src)[6],(src)[7]); } while (0)
#define SLOAD(dst, tyy, slot)  PLOAD(dst, sPm, ((tyy) * 2 + (slot)))
#define SSTORE(tyy, slot, src) PSTORE(sPm, ((tyy) * 2 + (slot)), src)

// ---------------- kernel 1: p0 = einsum(pad(x), w) + b_lin, planar [b][d][128][128]
__global__ __launch_bounds__(256) void einsum_kernel(
    const float* __restrict__ x, const float* __restrict__ w,
    const float* __restrict__ bl, float* __restrict__ p0)
{
    int id = blockIdx.x * 256 + threadIdx.x;
    int c = id & 127, r = (id >> 7) & 127, b = id >> 14;
    float acc[32];
#pragma unroll
    for (int d = 0; d < 32; ++d) acc[d] = bl[d];
    if (r >= 1 && r <= 126 && c >= 1 && c <= 126) {
        const float* xp = x + (((size_t)(b * 126 + (r - 1))) * 126 + (c - 1)) * 64;
#pragma unroll
        for (int f = 0; f < 64; f += 4) {
            float4 xv = *(const float4*)(xp + f);
#pragma unroll
            for (int d = 0; d < 32; ++d) {
                acc[d] += xv.x * w[d * 64 + f] + xv.y * w[d * 64 + f + 1]
                        + xv.z * w[d * 64 + f + 2] + xv.w * w[d * 64 + f + 3];
            }
        }
    }
    float* op = p0 + ((size_t)b * 32) * 16384 + r * 128 + c;
#pragma unroll
    for (int d = 0; d < 32; ++d) op[(size_t)d * 16384] = acc[d];
}

// ---------------- kernel 2: the full 3-outer-iteration simulation ----------------
// one workgroup per (b,d) plane; 512 threads = 16 tx (8 cols, DPP ring) x 32 ty (4 rows).
//
// Round-7: R6's DPP E/W exchange kept; its two regressions fixed:
//  (1) spill: u,v live as FULL PLANES in LDS (64K each); build_b/velocity stream
//      them through a 3-row register window; Jacobi live regs = pC+cb+temps ~ 88.
//  (2) bank conflicts: split-half row layout (see PLOAD) -> uniform bank load.
// p seams are a single 32K buffer (2 barriers/iter; R5 showed barriers are cheap).
// Total LDS = 160 KiB exactly (AITER fmha precedent on gfx950). 1 WG/CU is
// structural (grid == #CUs), so 160K costs nothing.
__global__ __launch_bounds__(512, 2) void sim_kernel(
    const float* __restrict__ u0, const float* __restrict__ v0,
    const float* __restrict__ p0ws, const float* __restrict__ x,
    const float* __restrict__ w, const float* __restrict__ bl,
    float* __restrict__ out, int use_ws)
{
    __shared__ float sU[128 * 128];   // 64 KiB  u plane (split-half rows)
    __shared__ float sV[128 * 128];   // 64 KiB  v plane
    __shared__ float sPm[32 * 2 * 128]; // 32 KiB p seam rows {0,3} per ty (single buffer)

    const int tid = threadIdx.x;
    const int tx = tid & 15, ty = tid >> 4;
    const int c0 = tx << 3, r0 = ty << 2;
    const int lane = tid & 63;
    const int bb = blockIdx.x & 7;   // batch
    const int d  = blockIdx.x >> 3;  // channel
    const int tyN = (ty > 0) ? ty - 1 : 0;     // clamped: garbage masked by BC overwrite
    const int tyS = (ty < 31) ? ty + 1 : 31;
    const int rowN = (r0 > 0) ? r0 - 1 : 0;        // clamped plane halo rows
    const int rowS = (r0 + 4 < 128) ? r0 + 4 : 127;

    // runtime DPP-direction probe: does ROW_ROR:1 source from lane-1 (mod 16)?
    const int pr = __builtin_amdgcn_mov_dpp(lane, 0x121, 0xF, 0xF, false);
    const bool selLower = (pr == ((lane & 48) | ((lane + 15) & 15)));

    float pC[4][8];

    // ---- load u, v from global (one-time) straight into LDS planes ----
#pragma unroll
    for (int r = 0; r < 4; ++r) {
        const size_t base = ((size_t)((bb * 128 + (r0 + r)) * 128 + c0)) * 32 + d;
        float ut[8], vt[8];
#pragma unroll
        for (int c = 0; c < 8; ++c) {
            ut[c] = u0[base + (size_t)c * 32];
            vt[c] = v0[base + (size_t)c * 32];
        }
        PSTORE(sU, r0 + r, ut);
        PSTORE(sV, r0 + r, vt);
    }

    // ---- initial p ----
    if (use_ws) {
        const float* pp = p0ws + ((size_t)(bb * 32 + d)) * 16384;
#pragma unroll
        for (int r = 0; r < 4; ++r) {
            float4 a = *(const float4*)(pp + (r0 + r) * 128 + c0);
            float4 b = *(const float4*)(pp + (r0 + r) * 128 + c0 + 4);
            pC[r][0] = a.x; pC[r][1] = a.y; pC[r][2] = a.z; pC[r][3] = a.w;
            pC[r][4] = b.x; pC[r][5] = b.y; pC[r][6] = b.z; pC[r][7] = b.w;
        }
    } else {
        const float blv = bl[d];
#pragma unroll
        for (int r = 0; r < 4; ++r) {
            const int gr = r0 + r;
#pragma unroll
            for (int c = 0; c < 8; ++c) {
                const int gc = c0 + c;
                float acc = blv;
                if (gr >= 1 && gr <= 126 && gc >= 1 && gc <= 126) {
                    const float* xp = x + (((size_t)(bb * 126 + (gr - 1))) * 126 + (gc - 1)) * 64;
                    for (int f = 0; f < 64; f += 4) {
                        float4 xv = *(const float4*)(xp + f);
                        acc += xv.x * w[d * 64 + f] + xv.y * w[d * 64 + f + 1]
                             + xv.z * w[d * 64 + f + 2] + xv.w * w[d * 64 + f + 3];
                    }
                }
                pC[r][c] = acc;
            }
        }
    }

    // ---- initial p seam publish ----
    SSTORE(ty, 0, pC[0]);
    SSTORE(ty, 1, pC[3]);
    __syncthreads();

    for (int outer = 0; outer < OUTER; ++outer) {
        // ================= build_b -> cb = CC * b (streamed from LDS planes) =========
        float cb[4][8];
        {
            float um[8], uc[8], up[8], vm[8], vc[8], vp[8];
            PLOAD(um, sU, rowN); PLOAD(vm, sV, rowN);
            PLOAD(uc, sU, r0);   PLOAD(vc, sV, r0);
#pragma unroll
            for (int r = 0; r < 4; ++r) {
                const int rn = (r < 3) ? (r0 + r + 1) : rowS;
                PLOAD(up, sU, rn); PLOAD(vp, sV, rn);
                float uWh = FROM_LO(uc[7]);
                float uEh = FROM_HI(uc[0]);
                float vWh = FROM_LO(vc[7]);
                float vEh = FROM_HI(vc[0]);
#pragma unroll
                for (int c = 0; c < 8; ++c) {
                    float uE = (c < 7) ? uc[c + 1] : uEh;
                    float uW = (c > 0) ? uc[c - 1] : uWh;
                    float vE = (c < 7) ? vc[c + 1] : vEh;
                    float vW = (c > 0) ? vc[c - 1] : vWh;
                    float dudx = (uE - uW) * INV2DX;
                    float dvdy = (vp[c] - vm[c]) * INV2DY;
                    float dudy = (up[c] - um[c]) * INV2DY;
                    float dvdx = (vE - vW) * INV2DX;
                    float bt = (dudx + dvdy) * INVDT - dudx * dudx
                             - 2.0f * dudy * dvdx - dvdy * dvdy;   // RHO == 1
                    cb[r][c] = CC * bt;   // garbage at rows 0/127: masked by p BCs
                }
#pragma unroll
                for (int c = 0; c < 8; ++c) {
                    um[c] = uc[c]; uc[c] = up[c];
                    vm[c] = vc[c]; vc[c] = vp[c];
                }
            }
        }
        // planes stable through Jacobi (only sPm written); no barrier needed here.

        // ================= pressure_poisson: 20 Jacobi iterations =================
        for (int it = 0; it < NITER; ++it) {
            float nrow[8], shalo[8];
            SLOAD(nrow, tyN, 1);    // old row r0-1
            SLOAD(shalo, tyS, 0);   // old row r0+4
#pragma unroll
            for (int r = 0; r < 4; ++r) {
                float old0[8];   // snapshot: ALL same-row neighbors must be OLD (Jacobi)
#pragma unroll
                for (int c = 0; c < 8; ++c) old0[c] = pC[r][c];
                float pWh = FROM_LO(old0[7]);
                float pEh = FROM_HI(old0[0]);
#pragma unroll
                for (int c = 0; c < 8; ++c) {
                    float E = (c < 7) ? old0[c + 1] : pEh;
                    float W = (c > 0) ? old0[c - 1] : pWh;
                    float N = nrow[c];
                    float S = (r < 3) ? pC[r + 1][c] : shalo[c];
                    pC[r][c] = (E + W) * K1 + (N + S) * K2 - cb[r][c];
                }
#pragma unroll
                for (int c = 0; c < 8; ++c) nrow[c] = old0[c];
            }
            // row BCs (copy of NEW values); also masks the garbage edge-row computes
            if (ty == 0) {
#pragma unroll
                for (int c = 0; c < 8; ++c) pC[0][c] = pC[1][c];
            }
            if (ty == 31) {
#pragma unroll
                for (int c = 0; c < 8; ++c) pC[3][c] = pC[2][c];
            }
            __syncthreads();        // all seam reads done before the rewrite
            SSTORE(ty, 0, pC[0]);
            SSTORE(ty, 1, pC[3]);
            __syncthreads();        // new seams visible for next iteration
        }

        // ================= velocity_step (skipped after last outer: output is p) ========
        if (outer < OUTER - 1) {
            // Pre-read ALL cross-thread plane rows (rowN, rowS) before any plane write.
            float uSh[8], vSh[8], um[8], uc[8], up[8], vm[8], vc[8], vp[8];
            PLOAD(uSh, sU, rowS); PLOAD(vSh, sV, rowS);
            PLOAD(um, sU, rowN);  PLOAD(vm, sV, rowN);
            PLOAD(uc, sU, r0);    PLOAD(vc, sV, r0);      // own rows
            PLOAD(up, sU, r0 + 1); PLOAD(vp, sV, r0 + 1); // own rows
            __syncthreads();   // halo reads complete; own-row writes below are private
            float pNh[8], pSh[8];
            SLOAD(pNh, tyN, 1);    // final p row r0-1 (sPm stable during velocity)
            SLOAD(pSh, tyS, 0);    // final p row r0+4
#pragma unroll
            for (int r = 0; r < 4; ++r) {
                float uWh = FROM_LO(uc[7]);
                float uEh = FROM_HI(uc[0]);
                float vWh = FROM_LO(vc[7]);
                float vEh = FROM_HI(vc[0]);
                float pWh = FROM_LO(pC[r][7]);
                float pEh = FROM_HI(pC[r][0]);
                float un[8], vn[8];
#pragma unroll
                for (int c = 0; c < 8; ++c) {
                    float ucc = uc[c], vcc = vc[c];
                    float uE = (c < 7) ? uc[c + 1] : uEh;
                    float uW = (c > 0) ? uc[c - 1] : uWh;
                    float vE = (c < 7) ? vc[c + 1] : vEh;
                    float vW = (c > 0) ? vc[c - 1] : vWh;
                    float uN = um[c], uS = up[c];
                    float vN = vm[c], vS = vp[c];
                    float pE = (c < 7) ? pC[r][c + 1] : pEh;
                    float pW = (c > 0) ? pC[r][c - 1] : pWh;
                    float pN = (r > 0) ? pC[r - 1][c] : pNh[c];
                    float pS = (r < 3) ? pC[r + 1][c] : pSh[c];

                    un[c] = ucc - ucc * DTDX * (ucc - uW) - vcc * DTDY * (ucc - uN)
                          - PGX * (pE - pW)
                          + NUf * (A1 * (uE - 2.0f * ucc + uW) + A2 * (uS - 2.0f * ucc + uN))
                          + FDT;
                    vn[c] = vcc - ucc * DTDX * (vcc - vW) - vcc * DTDY * (vcc - vN)
                          - PGY * (pS - pN)
                          + NUf * (A1 * (vE - 2.0f * vcc + vW) + A2 * (vS - 2.0f * vcc + vN));
                }
                // u,v row BCs: global rows 0 and 127 -> 0 (masks clamped-halo garbage)
                if (ty == 0 && r == 0) {
#pragma unroll
                    for (int c = 0; c < 8; ++c) { un[c] = 0.0f; vn[c] = 0.0f; }
                }
                if (ty == 31 && r == 3) {
#pragma unroll
                    for (int c = 0; c < 8; ++c) { un[c] = 0.0f; vn[c] = 0.0f; }
                }
                PSTORE(sU, r0 + r, un);   // own row; neighbors pre-read their halos
                PSTORE(sV, r0 + r, vn);
                // rotate window (old values preserved in registers)
#pragma unroll
                for (int c = 0; c < 8; ++c) {
                    um[c] = uc[c]; uc[c] = up[c];
                    vm[c] = vc[c]; vc[c] = vp[c];
                }
                if (r < 2) {
                    PLOAD(up, sU, r0 + r + 2);   // own rows, not yet rewritten
                    PLOAD(vp, sV, r0 + r + 2);
                } else if (r == 2) {
#pragma unroll
                    for (int c = 0; c < 8; ++c) { up[c] = uSh[c]; vp[c] = vSh[c]; }
                }
            }
            __syncthreads();   // plane writes complete before next outer's build_b reads
        }
    }

    // ---- output: p[:, row 127, :, :]  -> out[b][col][d] ----
    if (ty == 31) {
        float* op = out + ((size_t)bb * 128 + c0) * 32 + d;
#pragma unroll
        for (int c = 0; c < 8; ++c) op[(size_t)c * 32] = pC[3][c];
    }
}

extern "C" void kernel_launch(void* const* d_in, const int* in_sizes, int n_in,
                              void* d_out, int out_size, void* d_ws, size_t ws_size,
                              hipStream_t stream) {
    const float* x  = (const float*)d_in[0];
    const float* u0 = (const float*)d_in[1];
    const float* v0 = (const float*)d_in[2];
    const float* w  = (const float*)d_in[3];
    const float* bl = (const float*)d_in[4];
    float* out = (float*)d_out;
    float* p0  = (float*)d_ws;

    const size_t need = (size_t)8 * 32 * 128 * 128 * sizeof(float);
    const int use_ws = (ws_size >= need) ? 1 : 0;

    if (use_ws) {
        einsum_kernel<<<512, 256, 0, stream>>>(x, w, bl, p0);
    }
    sim_kernel<<<256, 512, 0, stream>>>(u0, v0, p0, x, w, bl, out, use_ws);
}